// Round 2
// baseline (137.099 us; speedup 1.0000x reference)
//
#include <hip/hip_runtime.h>
#include <hip/hip_bf16.h>
#include <math.h>

#define B_   16
#define T_   512
#define D_   2048
#define DS_  4096
#define TCHUNK 8
#define EPS_ 1e-8f

// ws layout (floats): num[B_*DS_] | inv_den[DS_] | neg_r[DS_] | er[DS_]  = 311,296 bytes

__global__ __launch_bounds__(256) void pre_kernel(const float* __restrict__ decay_rates,
                                                  float* __restrict__ num,
                                                  float* __restrict__ inv_den,
                                                  float* __restrict__ neg_r,
                                                  float* __restrict__ er) {
    int gtid = blockIdx.x * 256 + threadIdx.x;
    num[gtid] = 0.f;                       // zero accumulator (ws is poisoned 0xAA)
    if (gtid < DS_) {
        float x = decay_rates[gtid];
        // stable softplus: log1p(exp(x)) -> x for large x
        float r  = (x > 20.f) ? x : log1pf(expf(x));
        float nr = -r;
        float s = 0.f;
        for (int k = 0; k < T_; ++k) s += expf(nr * (float)k);   // sum_t decay (accurate path)
        inv_den[gtid] = 1.0f / sqrtf(s + EPS_);
        neg_r[gtid]   = nr;
        er[gtid]      = expf(r);           // per-step weight growth factor (<= e^r)
    }
}

__global__ __launch_bounds__(256) void main_kernel(const float* __restrict__ z,
                                                   const int* __restrict__ idx_i,
                                                   const int* __restrict__ idx_j,
                                                   const float* __restrict__ neg_r,
                                                   const float* __restrict__ er,
                                                   float* __restrict__ num) {
    __shared__ float rows[TCHUNK * D_];    // 8 rows x 2048 f32 = 64 KB -> 2 blocks/CU
    const int tc  = blockIdx.x;            // t-chunk 0..63
    const int b   = blockIdx.y;            // 0..15
    const int tid = threadIdx.x;

    // Stage 8 contiguous rows: 16384 consecutive floats, coalesced float4 loads.
    const float4* src4 = reinterpret_cast<const float4*>(z + ((size_t)b * T_ + (size_t)tc * TCHUNK) * D_);
    float4* lds4 = reinterpret_cast<float4*>(rows);
    #pragma unroll
    for (int v = 0; v < (TCHUNK * D_ / 4) / 256; ++v)
        lds4[tid + v * 256] = src4[tid + v * 256];
    __syncthreads();

    const int kbase = (T_ - 1) - tc * TCHUNK;   // exponent k = kbase - tl, always >= 0

    #pragma unroll 1
    for (int s = 0; s < DS_ / 256; ++s) {
        const int n  = tid + s * 256;
        const int ii = idx_i[n];
        const int jj = idx_j[n];
        // w(tl) = exp(-r*(kbase-tl)): start at tl=0, multiply by e^r each step.
        float w = __expf(neg_r[n] * (float)kbase);
        const float g = er[n];
        float acc = 0.f;
        #pragma unroll
        for (int tl = 0; tl < TCHUNK; ++tl) {
            acc += rows[tl * D_ + ii] * rows[tl * D_ + jj] * w;
            w *= g;
        }
        atomicAdd(&num[b * DS_ + n], acc);
    }
}

__global__ __launch_bounds__(256) void fin_kernel(const float* __restrict__ num,
                                                  const float* __restrict__ inv_den,
                                                  float* __restrict__ out) {
    int gtid = blockIdx.x * 256 + threadIdx.x;
    out[gtid] = num[gtid] * inv_den[gtid & (DS_ - 1)];
}

extern "C" void kernel_launch(void* const* d_in, const int* in_sizes, int n_in,
                              void* d_out, int out_size, void* d_ws, size_t ws_size,
                              hipStream_t stream) {
    const float* z  = (const float*)d_in[0];   // z_hist (16,512,2048) f32
    const float* dr = (const float*)d_in[1];   // decay_rates (4096,) f32
    const int*   ii = (const int*)d_in[2];     // idx_i (4096,) i32
    const int*   jj = (const int*)d_in[3];     // idx_j (4096,) i32
    float* out = (float*)d_out;                // (16,4096) f32

    float* num     = (float*)d_ws;             // B*DS
    float* inv_den = num + B_ * DS_;           // DS
    float* neg_r   = inv_den + DS_;            // DS
    float* er      = neg_r + DS_;              // DS

    hipLaunchKernelGGL(pre_kernel, dim3((B_ * DS_) / 256), dim3(256), 0, stream,
                       dr, num, inv_den, neg_r, er);
    hipLaunchKernelGGL(main_kernel, dim3(T_ / TCHUNK, B_), dim3(256), 0, stream,
                       z, ii, jj, neg_r, er, num);
    hipLaunchKernelGGL(fin_kernel, dim3((B_ * DS_) / 256), dim3(256), 0, stream,
                       num, inv_den, out);
}

// Round 4
// 135.421 us; speedup vs baseline: 1.0124x; 1.0124x over previous
//
#include <hip/hip_runtime.h>
#include <hip/hip_bf16.h>
#include <math.h>

#define B_   16
#define T_   512
#define D_   2048
#define DS_  4096
#define TCHUNK 4
#define EPS_ 1e-8f

// ws layout (floats): num[B_*DS_] | inv_den[DS_] | neg_r[DS_] | er[DS_]

__global__ __launch_bounds__(256) void pre_kernel(const float* __restrict__ decay_rates,
                                                  float* __restrict__ num,
                                                  float* __restrict__ inv_den,
                                                  float* __restrict__ neg_r,
                                                  float* __restrict__ er) {
    int gtid = blockIdx.x * 256 + threadIdx.x;
    num[gtid] = 0.f;                         // zero accumulator (ws is poisoned 0xAA)
    if (gtid < DS_) {
        float x = decay_rates[gtid];
        float r = (x > 20.f) ? x : log1pf(expf(x));   // stable softplus, r > 0
        // sum_{k=0}^{T-1} e^{-r k} = expm1(-r*T) / expm1(-r)  (exact geometric sum)
        float S = expm1f(-r * (float)T_) / expm1f(-r);
        inv_den[gtid] = 1.0f / sqrtf(S + EPS_);
        neg_r[gtid]   = -r;
        er[gtid]      = expf(r);             // per-t weight growth factor
    }
}

__global__ __launch_bounds__(256, 5) void main_kernel(const float* __restrict__ z,
                                                      const int* __restrict__ idx_i,
                                                      const int* __restrict__ idx_j,
                                                      const float* __restrict__ neg_r,
                                                      const float* __restrict__ er,
                                                      float* __restrict__ num) {
    // quads[c] = (row0[c], row1[c], row2[c], row3[c]) -> one b128 gathers 4 t-rows
    __shared__ float4 quads[D_];             // 32 KB -> 5 blocks/CU
    const int tc  = blockIdx.x;              // 0..127 (t-chunk of 4)
    const int b   = blockIdx.y;              // 0..15
    const int tid = threadIdx.x;
    const int t0  = tc * TCHUNK;
    const float* base = z + ((size_t)b * T_ + t0) * D_;

    // Stage: each thread fills whole quads -> LDS writes are lane-consecutive 16B
    #pragma unroll
    for (int it = 0; it < D_ / 256; ++it) {  // 8 iters
        int c = tid + it * 256;
        quads[c] = make_float4(base[c], base[D_ + c], base[2 * D_ + c], base[3 * D_ + c]);
    }
    __syncthreads();

    const int kbase = (T_ - 1) - t0;         // exponent for local row 0 (always >= 3)

    #pragma unroll 1
    for (int s = 0; s < DS_ / 256; ++s) {
        const int n  = tid + s * 256;
        const int ii = idx_i[n];
        const int jj = idx_j[n];
        const float g = er[n];
        const float w0 = __expf(neg_r[n] * (float)kbase);
        float4 vi = quads[ii];               // one ds_read_b128 = 4 rows
        float4 vj = quads[jj];
        float p0 = vi.x * vj.x;
        float p1 = vi.y * vj.y;
        float p2 = vi.z * vj.z;
        float p3 = vi.w * vj.w;
        // sum_k p_k * w0 * g^k  (Horner)
        float acc = w0 * (p0 + g * (p1 + g * (p2 + g * p3)));
        atomicAdd(&num[b * DS_ + n], acc);
    }
}

__global__ __launch_bounds__(256) void fin_kernel(const float* __restrict__ num,
                                                  const float* __restrict__ inv_den,
                                                  float* __restrict__ out) {
    int gtid = blockIdx.x * 256 + threadIdx.x;
    out[gtid] = num[gtid] * inv_den[gtid & (DS_ - 1)];
}

extern "C" void kernel_launch(void* const* d_in, const int* in_sizes, int n_in,
                              void* d_out, int out_size, void* d_ws, size_t ws_size,
                              hipStream_t stream) {
    const float* z  = (const float*)d_in[0];   // (16,512,2048) f32
    const float* dr = (const float*)d_in[1];   // (4096,) f32
    const int*   ii = (const int*)d_in[2];     // (4096,) i32
    const int*   jj = (const int*)d_in[3];     // (4096,) i32
    float* out = (float*)d_out;                // (16,4096) f32

    float* num     = (float*)d_ws;             // B*DS
    float* inv_den = num + B_ * DS_;           // DS
    float* neg_r   = inv_den + DS_;            // DS
    float* er      = neg_r + DS_;              // DS

    hipLaunchKernelGGL(pre_kernel, dim3((B_ * DS_) / 256), dim3(256), 0, stream,
                       dr, num, inv_den, neg_r, er);
    hipLaunchKernelGGL(main_kernel, dim3(T_ / TCHUNK, B_), dim3(256), 0, stream,
                       z, ii, jj, neg_r, er, num);
    hipLaunchKernelGGL(fin_kernel, dim3((B_ * DS_) / 256), dim3(256), 0, stream,
                       num, inv_den, out);
}